// Round 10
// baseline (228.751 us; speedup 1.0000x reference)
//
#include <hip/hip_runtime.h>

// GraphAttentionLayer: B=1, N=4096, F=256, H=8, U=64
//
// e_src cancels in softmax over j =>
//   out[i, u*8+h] = relu( (A @ (w*h))[i, h*64+u] / (A @ w)[i, h] ),  w = exp(e_dst)
// => ONE dense GEMM  C = A(4096x4096) x G(4096x544), G = [w*h (512) | w (8) | 0 (24)]
//
// R10 = R9 with ONE fix: phase 3 loaded ps[t] with t<512 threads but needs
// 544 entries -> den slots ps[512..543] were LDS garbage -> inf. Now strided.
//
// Single fused kernel (256 blocks x 512 thr), 2 manual grid barriers:
//  phase1 = R5 k_hg (2 units/block, 32-k W chunks, 43 KB LDS)
//  phase2 = R5 gemm VERBATIM (Z=4, 64 KB LDS union)
//  phase3 = k_out (16 rows/block)
// Co-residency: 64 KB LDS -> >=1 block/CU -> 256 blocks always resident.
// Cross-XCD: Gtp handoff via __threadfence at barrier; P via device atomics.
//
// ws: P @0 (8,912,896) | Gtp @8912896 (4,456,448) | bar @13369344 (16 B, memset 0)

typedef unsigned short u16;
typedef unsigned int   u32;
typedef __attribute__((ext_vector_type(8)))  short  short8;    // 8 bf16 (4 VGPR)
typedef __attribute__((ext_vector_type(16))) float  floatx16;  // 32x32 MFMA acc
typedef __attribute__((ext_vector_type(8)))  unsigned short u16x8;
typedef __attribute__((ext_vector_type(4)))  unsigned short u16x4;

__device__ __forceinline__ u16 f2bf(float x) {
  u32 u = __float_as_uint(x);
  u += 0x7fffu + ((u >> 16) & 1u);   // RNE
  return (u16)(u >> 16);
}

__device__ __forceinline__ void async_ld16(const void* g, void* l) {
  __builtin_amdgcn_global_load_lds((const __attribute__((address_space(1))) void*)g,
                                   (__attribute__((address_space(3))) void*)l,
                                   16, 0, 0);
}

// grid barrier: 256 blocks, counter c + flag f (both pre-zeroed by memset).
__device__ __forceinline__ void gbar(u32* c, u32* f) {
  __syncthreads();                       // all block writes issued (vmcnt drained)
  if (threadIdx.x == 0) {
    __threadfence();                     // release: L2 writeback (device scope)
    u32 old = atomicAdd(c, 1u);
    if (old == 255u) atomicExch(f, 1u);
    while (atomicAdd(f, 0u) == 0u) __builtin_amdgcn_s_sleep(2);
    __threadfence();                     // acquire: L1/L2 invalidate
  }
  __syncthreads();
}

__global__ __launch_bounds__(512, 2) void k_fused(const float* __restrict__ X,
                                                  const float* __restrict__ A,
                                                  const float* __restrict__ W,
                                                  const float* __restrict__ av,
                                                  u16* __restrict__ Gtp,
                                                  float* P,
                                                  float* __restrict__ out,
                                                  u32* bar) {
  __shared__ __align__(16) char smem[65536];
  const int b = blockIdx.x;
  const int t = threadIdx.x;

  // ================= phase 1: X@W + e_dst + exp -> Gtp (B-frag layout) ======
  {
    float* smf = (float*)smem;
    const int sub = t >> 8, tt = t & 255;          // 2 hg-units per block
    float* Wc  = smf + sub * 4096;                 // [2][32*128]
    float* xs  = smf + 8192 + sub * 1152;          // [2][32*36]
    float* eL  = smf + 10496 + sub * 64;
    float* w8L = smf + 10624 + sub * 64;
    const int bx = b & 127;
    const int y  = ((b >> 7) << 1) + sub;          // head pair 2y,2y+1
    const int j0 = bx * 32;
    const int c0 = y * 128;
    const int cq = tt & 31, tj = tt >> 5;

    // zero P: 557,056 float4 / 256 blocks = 2176 each
    {
      float4* P4 = (float4*)P;
      const int base = b * 2176;
      float4 z = {0.f, 0.f, 0.f, 0.f};
#pragma unroll
      for (int q = 0; q < 4; ++q) P4[base + q * 512 + t] = z;
      if (t < 128) P4[base + 2048 + t] = z;
    }
    if (tt < 64) eL[tt] = 0.f;

    float acc[4][4];
#pragma unroll
    for (int a = 0; a < 4; ++a)
#pragma unroll
      for (int q = 0; q < 4; ++q) acc[a][q] = 0.f;

    const int xjj = tt >> 3, xoff = (tt & 7) * 4;

    for (int cc = 0; cc < 8; ++cc) {               // K in 8 chunks of 32
#pragma unroll
      for (int l = 0; l < 4; ++l) {                // W chunk async -> LDS
        int id = l * 256 + tt;
        int kk = id >> 5, ch = id & 31;
        async_ld16(W + (size_t)(cc * 32 + kk) * 512 + c0 + ch * 4,
                   (char*)Wc + (size_t)(l * 256 + (tt & 192)) * 16);
      }
      {                                            // X chunk transposed
        const float* xp = X + (size_t)(j0 + xjj) * 256 + cc * 32 + xoff;
        float4 v = *(const float4*)xp;
        xs[(xoff + 0) * 36 + xjj] = v.x; xs[(xoff + 1) * 36 + xjj] = v.y;
        xs[(xoff + 2) * 36 + xjj] = v.z; xs[(xoff + 3) * 36 + xjj] = v.w;
      }
      __syncthreads();
#pragma unroll 4
      for (int kk = 0; kk < 32; ++kk) {
        float4 w4 = *(const float4*)(&Wc[kk * 128 + cq * 4]);
        float4 xa = *(const float4*)(&xs[kk * 36 + tj * 4]);   // broadcast
        acc[0][0] += xa.x * w4.x; acc[0][1] += xa.x * w4.y; acc[0][2] += xa.x * w4.z; acc[0][3] += xa.x * w4.w;
        acc[1][0] += xa.y * w4.x; acc[1][1] += xa.y * w4.y; acc[1][2] += xa.y * w4.z; acc[1][3] += xa.y * w4.w;
        acc[2][0] += xa.z * w4.x; acc[2][1] += xa.z * w4.y; acc[2][2] += xa.z * w4.z; acc[2][3] += xa.z * w4.w;
        acc[3][0] += xa.w * w4.x; acc[3][1] += xa.w * w4.y; acc[3][2] += xa.w * w4.z; acc[3][3] += xa.w * w4.w;
      }
      __syncthreads();
    }

    // e_dst partials (2 block-local heads per sub)
    const int lh = cq >> 4;
    {
      const float4 ad = *(const float4*)(av + 64 + (cq & 15) * 4);
#pragma unroll
      for (int jv = 0; jv < 4; ++jv) {
        float ep = acc[jv][0] * ad.x + acc[jv][1] * ad.y + acc[jv][2] * ad.z + acc[jv][3] * ad.w;
        atomicAdd(&eL[(tj * 4 + jv) * 2 + lh], ep);
      }
    }
    __syncthreads();
    if (tt < 64) {
      float e = fminf(30.f, fmaxf(-30.f, eL[tt]));
      w8L[tt] = __expf(e);
    }
    __syncthreads();

    // scaled bf16 stores in B-frag layout (HW-verified)
    const int tk  = (j0 >> 4) + (tj >> 2);
    const int khh = (tj >> 1) & 1;
    const int jlo = (tj & 1) * 4;
#pragma unroll
    for (int cv = 0; cv < 4; ++cv) {
      int n  = c0 + cq * 4 + cv;
      int nt = n >> 5;
      u16x4 o;
#pragma unroll
      for (int jv = 0; jv < 4; ++jv)
        o[jv] = f2bf(acc[jv][cv] * w8L[(tj * 4 + jv) * 2 + lh]);
      *(u16x4*)(Gtp + (size_t)(tk * 17 + nt) * 512 + ((n & 31) + 32 * khh) * 8 + jlo) = o;
    }
    if (tt < 64) {                       // den rows (n = 512 + h)
      int jj = tt >> 1, lh2 = tt & 1, h = 2 * y + lh2, j = j0 + jj;
      Gtp[(size_t)((j >> 4) * 17 + 16) * 512 + (h + 32 * ((jj & 15) >> 3)) * 8 + (jj & 7)] =
          f2bf(w8L[jj * 2 + lh2]);
    }
    if (y == 3 && tt < 96) {             // zero pad n in [520,544)
      int tk2 = tt / 48, r = tt - tk2 * 48;
      int slot = (r < 24) ? (8 + r) : (16 + r);
      u16x8 z = {0, 0, 0, 0, 0, 0, 0, 0};
      *(u16x8*)(Gtp + (size_t)(((j0 >> 4) + tk2) * 17 + 16) * 512 + slot * 8) = z;
    }
  }

  gbar(bar + 0, bar + 1);

  // ================= phase 2: gemm (R5 verbatim; b -> (i0, z)) ==============
  {
    u16* As0 = (u16*)smem;               // [64*256]
    u16* As1 = As0 + 64 * 256;
    const int i0   = (b & 63) * 64;
    const int kt0  = (b >> 6) * 1024;
    const int w    = t >> 6, lane = t & 63;
    const int wr   = w >> 2, wc = w & 3;
    const int ml   = lane & 31, kh = lane >> 5;

    floatx16 acc[5];
#pragma unroll
    for (int q = 0; q < 5; ++q)
#pragma unroll
      for (int r = 0; r < 16; ++r) acc[q][r] = 0.f;

    const int ar  = t >> 3;
    const int af  = (t & 7) * 4;
    const float* pa = A + (size_t)(i0 + ar) * 4096 + kt0 + af;
    const int sbase = ar * 256 + (t & 1) * 4;
    const int scb   = (t & 7) >> 1;
    const int arx   = ar & 7;
    const int arow  = (wr * 32 + ml) * 256;
    const int mx    = ml & 7;

    int nta[5];
#pragma unroll
    for (int q = 0; q < 5; ++q) { int v = wc + 4 * q; nta[q] = v < 17 ? v : 16; }

    float4 areg[8];
#pragma unroll
    for (int q = 0; q < 8; ++q) areg[q] = *(const float4*)(pa + q * 32);
#pragma unroll
    for (int q = 0; q < 8; ++q) {
      u16x4 v = {f2bf(areg[q].x), f2bf(areg[q].y), f2bf(areg[q].z), f2bf(areg[q].w)};
      *(u16x4*)(&As0[sbase + ((q * 4 + scb) ^ arx) * 8]) = v;
    }
    __syncthreads();

    for (int cc = 0; cc < 4; ++cc) {
      u16* Asb = (cc & 1) ? As1 : As0;
      u16* Asn = (cc & 1) ? As0 : As1;
      if (cc < 3) {
#pragma unroll
        for (int q = 0; q < 8; ++q)
          areg[q] = *(const float4*)(pa + (cc + 1) * 256 + q * 32);
      }
      const int ktb = (kt0 >> 4) + cc * 16;
#pragma unroll 2
      for (int ds = 0; ds < 8; ++ds) {
        short8 b0[5], b1[5];
#pragma unroll
        for (int q = 0; q < 5; ++q) {
          b0[q] = *(const short8*)(Gtp + (size_t)((ktb + ds * 2) * 17 + nta[q]) * 512 + lane * 8);
          b1[q] = *(const short8*)(Gtp + (size_t)((ktb + ds * 2 + 1) * 17 + nta[q]) * 512 + lane * 8);
        }
        short8 a0 = *(const short8*)(&Asb[arow + ((ds * 4 + kh) ^ mx) * 8]);
        short8 a1 = *(const short8*)(&Asb[arow + ((ds * 4 + 2 + kh) ^ mx) * 8]);
#pragma unroll
        for (int q = 0; q < 5; ++q)
          acc[q] = __builtin_amdgcn_mfma_f32_32x32x16_bf16(a0, b0[q], acc[q], 0, 0, 0);
#pragma unroll
        for (int q = 0; q < 5; ++q)
          acc[q] = __builtin_amdgcn_mfma_f32_32x32x16_bf16(a1, b1[q], acc[q], 0, 0, 0);
      }
      if (cc < 3) {
        __syncthreads();
#pragma unroll
        for (int q = 0; q < 8; ++q) {
          u16x4 v = {f2bf(areg[q].x), f2bf(areg[q].y), f2bf(areg[q].z), f2bf(areg[q].w)};
          *(u16x4*)(&Asn[sbase + ((q * 4 + scb) ^ arx) * 8]) = v;
        }
        __syncthreads();
      }
    }

    // epilogue: C/D col=lane&31, row=(r&3)+8*(r>>2)+4*(lane>>5); device atomics
    const int rbase = i0 + wr * 32 + 4 * kh;
#pragma unroll
    for (int q = 0; q < 5; ++q) {
      int n = (wc + 4 * q) * 32 + ml;
      if (n < 520) {
#pragma unroll
        for (int r = 0; r < 16; ++r) {
          int row = rbase + (r & 3) + 8 * (r >> 2);
          atomicAdd(P + (size_t)row * 544 + n, acc[q][r]);
        }
      }
    }
  }

  gbar(bar + 2, bar + 3);

  // ================= phase 3: out = relu(num/den), (u,h) permute ============
  {
    float* ps = (float*)smem;            // 544 floats
    for (int rr = 0; rr < 16; ++rr) {
      int row = b * 16 + rr;
      const float* pr = P + (size_t)row * 544;
      for (int q = t; q < 544; q += 512) ps[q] = pr[q];   // R9 bug: was if(t<544)
      __syncthreads();
      if (t < 512) {                     // t = u*8 + h
        int u = t >> 3, hd = t & 7;
        out[(size_t)row * 512 + t] = fmaxf(ps[hd * 64 + u] / ps[512 + hd], 0.f);
      }
      __syncthreads();
    }
  }
}

extern "C" void kernel_launch(void* const* d_in, const int* in_sizes, int n_in,
                              void* d_out, int out_size, void* d_ws, size_t ws_size,
                              hipStream_t stream) {
  const float* X  = (const float*)d_in[0];
  const float* A  = (const float*)d_in[1];
  const float* W  = (const float*)d_in[2];
  const float* av = (const float*)d_in[3];
  float* out = (float*)d_out;
  char*  ws  = (char*)d_ws;

  float* P   = (float*)ws;                 // 4096*544*4
  u16*   Gtp = (u16*)(ws + 8912896);       // 256*17 tiles * 1024 B
  u32*   bar = (u32*)(ws + 13369344);      // 2 x (counter, flag)

  hipMemsetAsync(bar, 0, 16, stream);
  k_fused<<<256, 512, 0, stream>>>(X, A, W, av, Gtp, P, out, bar);
}